// Round 18
// baseline (1518.840 us; speedup 1.0000x reference)
//
#include <hip/hip_runtime.h>
#include <stdint.h>

#define NQ 8192
#define NK 20000
#define RD 512
#define NT 157      // ceil(20000/128)
#define TS0 79      // split-0 tiles (keys 0..10111); split-1: 78 tiles (10112..20095, tail masked)

typedef float f32x4 __attribute__((ext_vector_type(4)));
typedef short s16x8 __attribute__((ext_vector_type(8)));

__device__ __forceinline__ unsigned short bf16_rn(float x) {
    uint32_t u = __float_as_uint(x);
    return (unsigned short)((u + 0x7FFFu + ((u >> 16) & 1)) >> 16);
}

// workgroup barrier that waits ONLY on LDS ops -- global loads stay in flight
// (plain __syncthreads() emits s_waitcnt vmcnt(0) which drains our prefetch pipeline)
__device__ __forceinline__ void lds_barrier() {
    asm volatile("s_waitcnt lgkmcnt(0)\n\ts_barrier" ::: "memory");
}

// ---------------- preconv: M(fp32) -> Mhi (RTZ hi), Mlo (RN residual), MT (RN bf16, transposed) ----
__global__ void preconv_kernel(const float* __restrict__ M,
                               unsigned short* __restrict__ Mhi,
                               unsigned short* __restrict__ Mlo,
                               unsigned short* __restrict__ MT) {
    __shared__ float tilef[64 * 65];
    const int k0 = blockIdx.x * 64, r0 = blockIdx.y * 64;
    const int t = threadIdx.x;
#pragma unroll
    for (int i = 0; i < 16; i++) {
        int e = t + i * 256;
        int kr = e >> 6, cc = e & 63;
        int key = k0 + kr;
        if (key < NK) {
            float x = M[(size_t)key * RD + r0 + cc];
            uint32_t u = __float_as_uint(x);
            Mhi[(size_t)key * RD + r0 + cc] = (unsigned short)(u >> 16);
            Mlo[(size_t)key * RD + r0 + cc] = bf16_rn(x - __uint_as_float(u & 0xFFFF0000u));
            tilef[cc * 65 + kr] = x;
        }
    }
    __syncthreads();
#pragma unroll
    for (int i = 0; i < 16; i++) {
        int e = t + i * 256;
        int rr = e >> 6, kk = e & 63;
        int key = k0 + kk;
        if (key < NK) MT[(size_t)(r0 + rr) * NK + key] = bf16_rn(tilef[rr * 65 + kk]);
    }
}

// one S-phase kstep of tile `ii` (v6 shape, K-pipe depth 2): consume slot s&1, refill with
// kstep s+2 (wraps into next tile), 4 qbuf reads, 12 MFMAs. Same MFMA order as flash6/12.
// Session laws (R6/R7/R9/R14): rotation depth must divide 16; arch-VGPR cap = 256/arg2;
// waves/CU step at total (arch+acc) regs {64,128,256}; 512-thr/73KB blocks never co-schedule
// 2/CU regardless of registers -> 8 waves/CU is this structure's residency ceiling.
#define S_STEP(ii, s_) do {                                                                        \
        const int sl_ = (s_) & 1;                                                                  \
        s16x8 kh0_ = kh[0][sl_], kl0_ = kl[0][sl_];                                                \
        s16x8 kh1_ = kh[1][sl_], kl1_ = kl[1][sl_];                                                \
        {                                                                                          \
            int g_ = (ii) * 16 + (s_) + 2;                                                         \
            size_t a0_ = kaddr(g_, 0), a1_ = kaddr(g_, 1);                                         \
            kh[0][sl_] = *(const s16x8*)(Mhi + a0_);                                               \
            kl[0][sl_] = *(const s16x8*)(Mlo + a0_);                                               \
            kh[1][sl_] = *(const s16x8*)(Mhi + a1_);                                               \
            kl[1][sl_] = *(const s16x8*)(Mlo + a1_);                                               \
        }                                                                                          \
        _Pragma("unroll")                                                                          \
        for (int st_ = 0; st_ < 2; st_++) {                                                       \
            s16x8 qh_ = *(const s16x8*)&qbuf[(st_ * 16 + (s_)) * 512 + l * 8];                     \
            s16x8 ql_ = *(const s16x8*)&qbuf[16384 + (st_ * 16 + (s_)) * 512 + l * 8];             \
            C[st_][0] = __builtin_amdgcn_mfma_f32_16x16x32_bf16(qh_, kh0_, C[st_][0], 0, 0, 0);    \
            C[st_][1] = __builtin_amdgcn_mfma_f32_16x16x32_bf16(qh_, kh1_, C[st_][1], 0, 0, 0);    \
            C[st_][0] = __builtin_amdgcn_mfma_f32_16x16x32_bf16(ql_, kh0_, C[st_][0], 0, 0, 0);    \
            C[st_][1] = __builtin_amdgcn_mfma_f32_16x16x32_bf16(ql_, kh1_, C[st_][1], 0, 0, 0);    \
            C[st_][0] = __builtin_amdgcn_mfma_f32_16x16x32_bf16(qh_, kl0_, C[st_][0], 0, 0, 0);    \
            C[st_][1] = __builtin_amdgcn_mfma_f32_16x16x32_bf16(qh_, kl1_, C[st_][1], 0, 0, 0);    \
        }                                                                                          \
    } while (0)

// ---------------- flash kernel v24: v23 + defer-max rescale (T13, THR=8) ---------------------
// v23 (1513 us) = v22 + setprio (verified -1.1%). v24 adds T13: when this tile's max exceeds
// the running max by <= 8 for every row the wave covers (wave-uniform __all; identical state
// in all waves), keep m_old -- skip the alpha exps and the O/Osum rescale (~80 serial VALU
// ops/tile in the barrier-locked softmax region). P is then bounded by e^8 instead of 1;
// fp32 accumulators and bf16 relative error are unaffected; mpart/lpart stay mutually
// consistent for the split-K combine. HK uses THR=8 (m214v23/m239: refchecks, +5% attn).
__global__ __launch_bounds__(256, 2) void flash24_kernel(
        const float* __restrict__ h,
        const unsigned short* __restrict__ Mhi,
        const unsigned short* __restrict__ Mlo,
        const unsigned short* __restrict__ MT,
        float* __restrict__ out,
        float* __restrict__ Opart,
        float* __restrict__ mpart,
        float* __restrict__ lpart,
        int nsplit) {
    __shared__ unsigned short qbuf[32768];   // 64 KB: [hi|lo] x (2 strips x 16 steps) x 512 u16
    __shared__ unsigned short pbuf[8 * 512]; // 8 KB: P frags (sk*2 + strip)
    __shared__ float smaxb[4 * 2 * 16];      // [ch][strip][row16]

    const int tid = threadIdx.x;
    const int ch = tid >> 6, l = tid & 63;
    const int l15 = l & 15, q4 = l >> 4;
    const int kq = (l15 >> 3) & 1, jj = l15 & 7;

    int qb, split;
    if (nsplit == 2) {
        // XCD-phase-aligned mapping (HW round-robin: block b -> XCD b%8; grid 512 = 8*64).
        // XCD x gets idx 0..63 with split = x>>2, qb = (x&3)*64 + idx  (bijective).
        int xcd = blockIdx.x & 7, idx = blockIdx.x >> 3;
        split = xcd >> 2;
        qb = (xcd & 3) * 64 + idx;
    } else { split = 0; qb = blockIdx.x; }
    const int koff = (split == 0) ? 0 : TS0 * 128;
    const int ntl  = (nsplit == 2) ? ((split == 0) ? TS0 : (NT - TS0)) : NT;
    const int total_ks = ntl * 16;
    const int qbase = qb * 32;

    // per-wave constant piece of every K address
    const size_t base_w = (size_t)(ch * 32 + l15) * RD + q4 * 8;
    auto kaddr = [&](int g, int cb) -> size_t {   // g = global kstep index (tile*16 + s)
        if (g >= total_ks) g = total_ks - 1;      // clamp: harmless reload of last kstep
        int t2 = g >> 4, s2 = g & 15;
        return (size_t)(koff + t2 * 128) * RD + (size_t)s2 * 32 + base_w + (size_t)cb * (16 * RD);
    };

    // ---- prime K pipeline depth 2 (in flight during Q staging) ----
    s16x8 kh[2][2], kl[2][2];
#pragma unroll
    for (int i = 0; i < 2; i++) {
        size_t a0 = kaddr(i, 0), a1 = kaddr(i, 1);
        kh[0][i] = *(const s16x8*)(Mhi + a0);
        kl[0][i] = *(const s16x8*)(Mlo + a0);
        kh[1][i] = *(const s16x8*)(Mhi + a1);
        kl[1][i] = *(const s16x8*)(Mlo + a1);
    }

    // ---- stage Q -> LDS (hi RTZ / lo RN), frag-linear ----
#pragma unroll
    for (int i = 0; i < 8; i++) {
        int g = tid + i * 256;                  // 0..2047 = row*64 + s*4 + qg
        int row = g >> 6, s = (g >> 2) & 15, qg = g & 3;
        int strip = row >> 4, lrow = row & 15;
        const float* src = h + (size_t)(qbase + row) * RD + s * 32 + qg * 8;
        f32x4 a = *(const f32x4*)src;
        f32x4 b = *(const f32x4*)(src + 4);
        s16x8 hi8, lo8;
#pragma unroll
        for (int j = 0; j < 8; j++) {
            float x = (j < 4) ? a[j] : b[j - 4];
            uint32_t u = __float_as_uint(x);
            hi8[j] = (short)(u >> 16);
            lo8[j] = (short)bf16_rn(x - __uint_as_float(u & 0xFFFF0000u));
        }
        int off = ((strip * 16 + s) * 512 + (qg * 16 + lrow) * 8);
        *(s16x8*)&qbuf[off] = hi8;
        *(s16x8*)&qbuf[16384 + off] = lo8;
    }
    lds_barrier();      // qbuf visible; K prime stays in flight

    // ones fragment (bf16 1.0 x8) for the PV row-sum column
    s16x8 onesf;
#pragma unroll
    for (int j = 0; j < 8; j++) onesf[j] = (short)0x3F80;

    f32x4 O[2][8];
#pragma unroll
    for (int st = 0; st < 2; st++)
#pragma unroll
        for (int ct = 0; ct < 8; ct++) O[st][ct] = 0.f;
    f32x4 Osum[2];                  // running softmax denominators (same recurrence as O)
    Osum[0] = 0.f; Osum[1] = 0.f;
    f32x4 m_run[2];
    m_run[0] = -3e38f; m_run[1] = -3e38f;

    for (int tile = 0; tile < ntl; tile++) {
        // ================= S phase: depth-2 pipeline, prefetch wraps into next tile ==========
        f32x4 C[2][2];
        C[0][0] = 0.f; C[0][1] = 0.f; C[1][0] = 0.f; C[1][1] = 0.f;
        __builtin_amdgcn_s_setprio(1);          // MFMA-dense region: prefer this wave
#pragma unroll
        for (int s = 0; s < 16; s++) S_STEP(tile, s);
        __builtin_amdgcn_s_setprio(0);
        // mask tail keys
        if (tile == ntl - 1) {
#pragma unroll
            for (int cb = 0; cb < 2; cb++) {
                int kg = koff + tile * 128 + ch * 32 + cb * 16 + l15;
                if (kg >= NK) { C[0][cb] = -3e38f; C[1][cb] = -3e38f; }
            }
        }

        // PV B prologue: key-slice groups sk=0,1 (8 ct-frags each) -- in flight through softmax
        const unsigned short* mtp = MT + (size_t)(ch * 128 + l15) * NK + koff + tile * 128 + q4 * 8;
        s16x8 btg[2][8];
#pragma unroll
        for (int ct = 0; ct < 8; ct++) {
            btg[0][ct] = *(const s16x8*)(mtp + (size_t)ct * 16 * NK);
            btg[1][ct] = *(const s16x8*)(mtp + (size_t)ct * 16 * NK + 32);
        }

        // ================= softmax (max only -- sums come from PV) =================
        f32x4 mx[2];
#pragma unroll
        for (int st = 0; st < 2; st++)
#pragma unroll
            for (int v = 0; v < 4; v++) mx[st][v] = fmaxf(C[st][0][v], C[st][1][v]);
#pragma unroll
        for (int d = 1; d < 16; d <<= 1) {
#pragma unroll
            for (int st = 0; st < 2; st++)
#pragma unroll
                for (int v = 0; v < 4; v++) mx[st][v] = fmaxf(mx[st][v], __shfl_xor(mx[st][v], d, 16));
        }
        if (l15 == 0) {
            *(f32x4*)&smaxb[(ch * 2 + 0) * 16 + q4 * 4] = mx[0];
            *(f32x4*)&smaxb[(ch * 2 + 1) * 16 + q4 * 4] = mx[1];
        }
        lds_barrier();   // B1 (lgkm only -- K/btg prefetches stay in flight)
        f32x4 mnew[2]; mnew[0] = m_run[0]; mnew[1] = m_run[1];
#pragma unroll
        for (int cc = 0; cc < 4; cc++) {
#pragma unroll
            for (int st = 0; st < 2; st++) {
                f32x4 tv = *(const f32x4*)&smaxb[(cc * 2 + st) * 16 + q4 * 4];
#pragma unroll
                for (int v = 0; v < 4; v++) mnew[st][v] = fmaxf(mnew[st][v], tv[v]);
            }
        }
        // T13 defer-max: skip rescale when every row's growth <= 8 (wave-uniform; identical
        // per-row state in all waves -> consistent decision across the block).
        float dmax = 0.f;
#pragma unroll
        for (int st = 0; st < 2; st++)
#pragma unroll
            for (int v = 0; v < 4; v++) dmax = fmaxf(dmax, mnew[st][v] - m_run[st][v]);
        const bool resc = !__all(dmax <= 8.0f);
        f32x4 alpha[2];
        if (resc) {
#pragma unroll
            for (int st = 0; st < 2; st++)
#pragma unroll
                for (int v = 0; v < 4; v++) {
                    alpha[st][v] = __expf(m_run[st][v] - mnew[st][v]);
                    m_run[st][v] = mnew[st][v];
                }
        }
        // p relative to the (possibly kept) running max; bounded by e^8 when deferred
#pragma unroll
        for (int st = 0; st < 2; st++) {
#pragma unroll
            for (int cb = 0; cb < 2; cb++) {
#pragma unroll
                for (int v = 0; v < 4; v++) {
                    float p = __expf(C[st][cb][v] - m_run[st][v]);
                    pbuf[(ch * 2 + st) * 512 + ((cb * 2 + kq) * 16 + q4 * 4 + v) * 8 + jj] = bf16_rn(p);
                }
            }
        }
        lds_barrier();   // B2: pbuf visible to all waves before pa reads
        if (resc) {
#pragma unroll
            for (int st = 0; st < 2; st++) {
#pragma unroll
                for (int ct = 0; ct < 8; ct++)
#pragma unroll
                    for (int v = 0; v < 4; v++) O[st][ct][v] *= alpha[st][v];
#pragma unroll
                for (int v = 0; v < 4; v++) Osum[st][v] *= alpha[st][v];
            }
        }

        // ================= PV phase: sk-outer, group prefetch distance >= 1 group ============
        __builtin_amdgcn_s_setprio(1);          // MFMA-dense region: prefer this wave
#pragma unroll
        for (int sk = 0; sk < 4; sk++) {
            s16x8 pa0 = *(const s16x8*)&pbuf[((sk * 2 + 0) * 512) + l * 8];
            s16x8 pa1 = *(const s16x8*)&pbuf[((sk * 2 + 1) * 512) + l * 8];
            s16x8 b0 = btg[sk & 1][0], b1 = btg[sk & 1][1], b2 = btg[sk & 1][2], b3 = btg[sk & 1][3];
            s16x8 b4 = btg[sk & 1][4], b5 = btg[sk & 1][5], b6 = btg[sk & 1][6], b7 = btg[sk & 1][7];
            if (sk < 2) {
#pragma unroll
                for (int ct = 0; ct < 8; ct++)
                    btg[sk & 1][ct] = *(const s16x8*)(mtp + (size_t)ct * 16 * NK + (sk + 2) * 32);
            }
            O[0][0] = __builtin_amdgcn_mfma_f32_16x16x32_bf16(pa0, b0, O[0][0], 0, 0, 0);
            O[1][0] = __builtin_amdgcn_mfma_f32_16x16x32_bf16(pa1, b0, O[1][0], 0, 0, 0);
            O[0][1] = __builtin_amdgcn_mfma_f32_16x16x32_bf16(pa0, b1, O[0][1], 0, 0, 0);
            O[1][1] = __builtin_amdgcn_mfma_f32_16x16x32_bf16(pa1, b1, O[1][1], 0, 0, 0);
            O[0][2] = __builtin_amdgcn_mfma_f32_16x16x32_bf16(pa0, b2, O[0][2], 0, 0, 0);
            O[1][2] = __builtin_amdgcn_mfma_f32_16x16x32_bf16(pa1, b2, O[1][2], 0, 0, 0);
            O[0][3] = __builtin_amdgcn_mfma_f32_16x16x32_bf16(pa0, b3, O[0][3], 0, 0, 0);
            O[1][3] = __builtin_amdgcn_mfma_f32_16x16x32_bf16(pa1, b3, O[1][3], 0, 0, 0);
            O[0][4] = __builtin_amdgcn_mfma_f32_16x16x32_bf16(pa0, b4, O[0][4], 0, 0, 0);
            O[1][4] = __builtin_amdgcn_mfma_f32_16x16x32_bf16(pa1, b4, O[1][4], 0, 0, 0);
            O[0][5] = __builtin_amdgcn_mfma_f32_16x16x32_bf16(pa0, b5, O[0][5], 0, 0, 0);
            O[1][5] = __builtin_amdgcn_mfma_f32_16x16x32_bf16(pa1, b5, O[1][5], 0, 0, 0);
            O[0][6] = __builtin_amdgcn_mfma_f32_16x16x32_bf16(pa0, b6, O[0][6], 0, 0, 0);
            O[1][6] = __builtin_amdgcn_mfma_f32_16x16x32_bf16(pa1, b6, O[1][6], 0, 0, 0);
            O[0][7] = __builtin_amdgcn_mfma_f32_16x16x32_bf16(pa0, b7, O[0][7], 0, 0, 0);
            O[1][7] = __builtin_amdgcn_mfma_f32_16x16x32_bf16(pa1, b7, O[1][7], 0, 0, 0);
            // row-sum column: Osum += P . ones  (exact fp32 accumulate of the same bf16(p))
            Osum[0] = __builtin_amdgcn_mfma_f32_16x16x32_bf16(pa0, onesf, Osum[0], 0, 0, 0);
            Osum[1] = __builtin_amdgcn_mfma_f32_16x16x32_bf16(pa1, onesf, Osum[1], 0, 0, 0);
        }
        __builtin_amdgcn_s_setprio(0);
        // no trailing barrier: B1 of the next iteration orders pa-reads vs pbuf-writes
    }

    // ================= epilogue =================
    if (nsplit == 2) {
        float* Od = Opart + (size_t)split * NQ * RD;
#pragma unroll
        for (int st = 0; st < 2; st++)
#pragma unroll
            for (int ct = 0; ct < 8; ct++)
#pragma unroll
                for (int v = 0; v < 4; v++)
                    Od[(size_t)(qbase + st * 16 + q4 * 4 + v) * RD + ch * 128 + ct * 16 + l15] =
                        O[st][ct][v];
        if (ch == 0 && l15 == 0) {
#pragma unroll
            for (int st = 0; st < 2; st++)
#pragma unroll
                for (int v = 0; v < 4; v++) {
                    mpart[split * NQ + qbase + st * 16 + q4 * 4 + v] = m_run[st][v];
                    lpart[split * NQ + qbase + st * 16 + q4 * 4 + v] = Osum[st][v];
                }
        }
    } else {
#pragma unroll
        for (int st = 0; st < 2; st++)
#pragma unroll
            for (int ct = 0; ct < 8; ct++)
#pragma unroll
                for (int v = 0; v < 4; v++)
                    out[(size_t)(qbase + st * 16 + q4 * 4 + v) * RD + ch * 128 + ct * 16 + l15] =
                        O[st][ct][v] / Osum[st][v];
    }
}

// ---------------- combine split-K partials ----------------
__global__ __launch_bounds__(256) void combine_kernel(const float* __restrict__ Opart,
                                                      const float* __restrict__ mpart,
                                                      const float* __restrict__ lpart,
                                                      float* __restrict__ out) {
    const int t = threadIdx.x;
    const int row = blockIdx.x * 2 + (t >> 7);
    const int d = (t & 127) * 4;
    float m0 = mpart[row], m1 = mpart[NQ + row];
    float l0 = lpart[row], l1 = lpart[NQ + row];
    float m = fmaxf(m0, m1);
    float w0 = __expf(m0 - m), w1 = __expf(m1 - m);
    float inv = 1.f / (w0 * l0 + w1 * l1);
    f32x4 o0 = *(const f32x4*)&Opart[(size_t)row * RD + d];
    f32x4 o1 = *(const f32x4*)&Opart[(size_t)NQ * RD + (size_t)row * RD + d];
    f32x4 r;
#pragma unroll
    for (int v = 0; v < 4; v++) r[v] = (o0[v] * w0 + o1[v] * w1) * inv;
    *(f32x4*)&out[(size_t)row * RD + d] = r;
}

// ---------------- fallback (ws too small): fp32, slow but exact ----------------
__global__ __launch_bounds__(256) void naive_kernel(const float* __restrict__ h,
                                                    const float* __restrict__ M,
                                                    float* __restrict__ out) {
    __shared__ float hs[16 * 520];
    __shared__ float ms[8 * 520];
    __shared__ float sdot[2][128];
    __shared__ float sm[16], sl[16], sal[16], sp[16][8];
    const int t = threadIdx.x;
    const int qbase = blockIdx.x * 16;
#pragma unroll
    for (int i = 0; i < 32; i++) {
        int e = t + i * 256;
        int row = e >> 9, col = e & 511;
        hs[row * 520 + col] = h[(size_t)(qbase + row) * RD + col];
    }
    if (t < 16) { sm[t] = -3e38f; sl[t] = 0.f; }
    float Oacc[32];
#pragma unroll
    for (int i = 0; i < 32; i++) Oacc[i] = 0.f;
    const int q = t >> 4;
    const int eb = (t & 15) * 32;

    for (int k0 = 0; k0 < NK; k0 += 8) {
        __syncthreads();
#pragma unroll
        for (int i = 0; i < 16; i++) {
            int e = t + i * 256;
            if (e < 4096) {
                int kk = e >> 9, col = e & 511;
                ms[kk * 520 + col] = M[(size_t)(k0 + kk) * RD + col];
            }
        }
        __syncthreads();
        {
            int pair = t & 127, half = t >> 7;
            int qq = pair & 15, kk = pair >> 4;
            const float* hp = &hs[qq * 520 + half * 256];
            const float* mp = &ms[kk * 520 + half * 256];
            float acc = 0.f;
#pragma unroll 8
            for (int e = 0; e < 256; e++) acc += hp[e] * mp[e];
            sdot[half][pair] = acc;
        }
        __syncthreads();
        if (t < 16) {
            int qq = t;
            float s8[8];
#pragma unroll
            for (int kk = 0; kk < 8; kk++) s8[kk] = sdot[0][qq + 16 * kk] + sdot[1][qq + 16 * kk];
            float mn = sm[qq];
#pragma unroll
            for (int kk = 0; kk < 8; kk++) mn = fmaxf(mn, s8[kk]);
            float al = __expf(sm[qq] - mn);
            float addl = 0.f;
#pragma unroll
            for (int kk = 0; kk < 8; kk++) { float p = __expf(s8[kk] - mn); sp[qq][kk] = p; addl += p; }
            sm[qq] = mn; sl[qq] = sl[qq] * al + addl; sal[qq] = al;
        }
        __syncthreads();
        {
            float al = sal[q];
#pragma unroll
            for (int i = 0; i < 32; i++) Oacc[i] *= al;
#pragma unroll
            for (int kk = 0; kk < 8; kk++) {
                float p = sp[q][kk];
                const float* mp = &ms[kk * 520 + eb];
#pragma unroll
                for (int i = 0; i < 32; i++) Oacc[i] += p * mp[i];
            }
        }
    }
    __syncthreads();
    float inv = 1.f / sl[q];
#pragma unroll
    for (int i = 0; i < 32; i++) out[(size_t)(qbase + q) * RD + eb + i] = Oacc[i] * inv;
}

extern "C" void kernel_launch(void* const* d_in, const int* in_sizes, int n_in,
                              void* d_out, int out_size, void* d_ws, size_t ws_size,
                              hipStream_t stream) {
    const float* h = (const float*)d_in[0];
    const float* M = (const float*)d_in[1];
    float* out = (float*)d_out;
    const size_t seg = (size_t)NK * RD;                      // u16 elems per converted buffer
    // Mhi + Mlo + MT + 8K u16 pad (tail reads stay in d_ws; 0xAA poison = finite bf16)
    const size_t base_bytes = (seg * 3ull + 8192ull) * 2ull;
    const size_t opart_bytes = 2ull * NQ * RD * 4ull;
    const size_t stat_bytes = 2ull * 2ull * NQ * 4ull;
    const size_t need_split = base_bytes + opart_bytes + stat_bytes;

    if (ws_size >= base_bytes) {
        unsigned short* Mhi = (unsigned short*)d_ws;
        unsigned short* Mlo = Mhi + seg;
        unsigned short* MT  = Mlo + seg;
        float* Opart = (float*)((char*)d_ws + base_bytes);
        float* mpart = Opart + 2ull * NQ * RD;
        float* lpart = mpart + 2ull * NQ;
        preconv_kernel<<<dim3(313, 8), 256, 0, stream>>>(M, Mhi, Mlo, MT);
        if (ws_size >= need_split) {
            flash24_kernel<<<512, 256, 0, stream>>>(h, Mhi, Mlo, MT, out, Opart, mpart, lpart, 2);
            combine_kernel<<<NQ / 2, 256, 0, stream>>>(Opart, mpart, lpart, out);
        } else {
            flash24_kernel<<<256, 256, 0, stream>>>(h, Mhi, Mlo, MT, out, Opart, mpart, lpart, 1);
        }
    } else {
        naive_kernel<<<512, 256, 0, stream>>>(h, M, out);
    }
}

// Round 19
// 1505.025 us; speedup vs baseline: 1.0092x; 1.0092x over previous
//
#include <hip/hip_runtime.h>
#include <stdint.h>

#define NQ 8192
#define NK 20000
#define RD 512
#define NT 157      // ceil(20000/128)
#define TS0 79      // split-0 tiles (keys 0..10111); split-1: 78 tiles (10112..20095, tail masked)

typedef float f32x4 __attribute__((ext_vector_type(4)));
typedef short s16x8 __attribute__((ext_vector_type(8)));

__device__ __forceinline__ unsigned short bf16_rn(float x) {
    uint32_t u = __float_as_uint(x);
    return (unsigned short)((u + 0x7FFFu + ((u >> 16) & 1)) >> 16);
}

// workgroup barrier that waits ONLY on LDS ops -- global loads stay in flight
// (plain __syncthreads() emits s_waitcnt vmcnt(0) which drains our prefetch pipeline)
__device__ __forceinline__ void lds_barrier() {
    asm volatile("s_waitcnt lgkmcnt(0)\n\ts_barrier" ::: "memory");
}

// ---------------- preconv: M(fp32) -> Mhi (RTZ hi), Mlo (RN residual), MT (RN bf16, transposed) ----
__global__ void preconv_kernel(const float* __restrict__ M,
                               unsigned short* __restrict__ Mhi,
                               unsigned short* __restrict__ Mlo,
                               unsigned short* __restrict__ MT) {
    __shared__ float tilef[64 * 65];
    const int k0 = blockIdx.x * 64, r0 = blockIdx.y * 64;
    const int t = threadIdx.x;
#pragma unroll
    for (int i = 0; i < 16; i++) {
        int e = t + i * 256;
        int kr = e >> 6, cc = e & 63;
        int key = k0 + kr;
        if (key < NK) {
            float x = M[(size_t)key * RD + r0 + cc];
            uint32_t u = __float_as_uint(x);
            Mhi[(size_t)key * RD + r0 + cc] = (unsigned short)(u >> 16);
            Mlo[(size_t)key * RD + r0 + cc] = bf16_rn(x - __uint_as_float(u & 0xFFFF0000u));
            tilef[cc * 65 + kr] = x;
        }
    }
    __syncthreads();
#pragma unroll
    for (int i = 0; i < 16; i++) {
        int e = t + i * 256;
        int rr = e >> 6, kk = e & 63;
        int key = k0 + kk;
        if (key < NK) MT[(size_t)(r0 + rr) * NK + key] = bf16_rn(tilef[rr * 65 + kk]);
    }
}

// one S-phase kstep of tile `ii` (v6 shape, K-pipe depth 2): consume slot s&1, refill with
// kstep s+2 (wraps into next tile), 4 qbuf reads, 12 MFMAs. Same MFMA order as flash6/12.
// Session laws (R6/R7/R9/R14): rotation depth must divide 16; arch-VGPR cap = 256/arg2;
// waves/CU step at total (arch+acc) regs {64,128,256}; 512-thr/73KB blocks never co-schedule
// 2/CU regardless of registers -> 8 waves/CU is this structure's residency ceiling.
#define S_STEP(ii, s_) do {                                                                        \
        const int sl_ = (s_) & 1;                                                                  \
        s16x8 kh0_ = kh[0][sl_], kl0_ = kl[0][sl_];                                                \
        s16x8 kh1_ = kh[1][sl_], kl1_ = kl[1][sl_];                                                \
        {                                                                                          \
            int g_ = (ii) * 16 + (s_) + 2;                                                         \
            size_t a0_ = kaddr(g_, 0), a1_ = kaddr(g_, 1);                                         \
            kh[0][sl_] = *(const s16x8*)(Mhi + a0_);                                               \
            kl[0][sl_] = *(const s16x8*)(Mlo + a0_);                                               \
            kh[1][sl_] = *(const s16x8*)(Mhi + a1_);                                               \
            kl[1][sl_] = *(const s16x8*)(Mlo + a1_);                                               \
        }                                                                                          \
        _Pragma("unroll")                                                                          \
        for (int st_ = 0; st_ < 2; st_++) {                                                       \
            s16x8 qh_ = *(const s16x8*)&qbuf[(st_ * 16 + (s_)) * 512 + l * 8];                     \
            s16x8 ql_ = *(const s16x8*)&qbuf[16384 + (st_ * 16 + (s_)) * 512 + l * 8];             \
            C[st_][0] = __builtin_amdgcn_mfma_f32_16x16x32_bf16(qh_, kh0_, C[st_][0], 0, 0, 0);    \
            C[st_][1] = __builtin_amdgcn_mfma_f32_16x16x32_bf16(qh_, kh1_, C[st_][1], 0, 0, 0);    \
            C[st_][0] = __builtin_amdgcn_mfma_f32_16x16x32_bf16(ql_, kh0_, C[st_][0], 0, 0, 0);    \
            C[st_][1] = __builtin_amdgcn_mfma_f32_16x16x32_bf16(ql_, kh1_, C[st_][1], 0, 0, 0);    \
            C[st_][0] = __builtin_amdgcn_mfma_f32_16x16x32_bf16(qh_, kl0_, C[st_][0], 0, 0, 0);    \
            C[st_][1] = __builtin_amdgcn_mfma_f32_16x16x32_bf16(qh_, kl1_, C[st_][1], 0, 0, 0);    \
        }                                                                                          \
    } while (0)

// ---------------- flash kernel v25 (= v23, session best: 1513 us) ----------------------------
// FINAL STATE. v23 = tile-pipelined PV group prefetch + XCD-phase map + ones-column
// denominators + setprio around MFMA clusters. Session's verified wins: PV long-range
// B-prefetch (-52 us), XCD map + Osum-by-MFMA (-17 us), setprio (-17 us); total 1588 -> 1513.
// Measured-closed levers: softmax/S interleave (v7 ~0), 2x TLP (v9/v17/v19/v20/v21: blocked
// by the 128-reg x 73KB-LDS x 8-waves/CU residency bind), K-pipe depth>=4 (v14/v16), BM=16
// (v11), defer-max T13 (v24 +1%: branch overhead + 128-reg cap edge). Latency-bound local
// minimum (MfmaUtil 19.7%, HBM 1.4%) -- not a hardware roofline, but the practical floor of
// this structure on this toolchain.
__global__ __launch_bounds__(256, 2) void flash25_kernel(
        const float* __restrict__ h,
        const unsigned short* __restrict__ Mhi,
        const unsigned short* __restrict__ Mlo,
        const unsigned short* __restrict__ MT,
        float* __restrict__ out,
        float* __restrict__ Opart,
        float* __restrict__ mpart,
        float* __restrict__ lpart,
        int nsplit) {
    __shared__ unsigned short qbuf[32768];   // 64 KB: [hi|lo] x (2 strips x 16 steps) x 512 u16
    __shared__ unsigned short pbuf[8 * 512]; // 8 KB: P frags (sk*2 + strip)
    __shared__ float smaxb[4 * 2 * 16];      // [ch][strip][row16]

    const int tid = threadIdx.x;
    const int ch = tid >> 6, l = tid & 63;
    const int l15 = l & 15, q4 = l >> 4;
    const int kq = (l15 >> 3) & 1, jj = l15 & 7;

    int qb, split;
    if (nsplit == 2) {
        // XCD-phase-aligned mapping (HW round-robin: block b -> XCD b%8; grid 512 = 8*64).
        // XCD x gets idx 0..63 with split = x>>2, qb = (x&3)*64 + idx  (bijective).
        int xcd = blockIdx.x & 7, idx = blockIdx.x >> 3;
        split = xcd >> 2;
        qb = (xcd & 3) * 64 + idx;
    } else { split = 0; qb = blockIdx.x; }
    const int koff = (split == 0) ? 0 : TS0 * 128;
    const int ntl  = (nsplit == 2) ? ((split == 0) ? TS0 : (NT - TS0)) : NT;
    const int total_ks = ntl * 16;
    const int qbase = qb * 32;

    // per-wave constant piece of every K address
    const size_t base_w = (size_t)(ch * 32 + l15) * RD + q4 * 8;
    auto kaddr = [&](int g, int cb) -> size_t {   // g = global kstep index (tile*16 + s)
        if (g >= total_ks) g = total_ks - 1;      // clamp: harmless reload of last kstep
        int t2 = g >> 4, s2 = g & 15;
        return (size_t)(koff + t2 * 128) * RD + (size_t)s2 * 32 + base_w + (size_t)cb * (16 * RD);
    };

    // ---- prime K pipeline depth 2 (in flight during Q staging) ----
    s16x8 kh[2][2], kl[2][2];
#pragma unroll
    for (int i = 0; i < 2; i++) {
        size_t a0 = kaddr(i, 0), a1 = kaddr(i, 1);
        kh[0][i] = *(const s16x8*)(Mhi + a0);
        kl[0][i] = *(const s16x8*)(Mlo + a0);
        kh[1][i] = *(const s16x8*)(Mhi + a1);
        kl[1][i] = *(const s16x8*)(Mlo + a1);
    }

    // ---- stage Q -> LDS (hi RTZ / lo RN), frag-linear ----
#pragma unroll
    for (int i = 0; i < 8; i++) {
        int g = tid + i * 256;                  // 0..2047 = row*64 + s*4 + qg
        int row = g >> 6, s = (g >> 2) & 15, qg = g & 3;
        int strip = row >> 4, lrow = row & 15;
        const float* src = h + (size_t)(qbase + row) * RD + s * 32 + qg * 8;
        f32x4 a = *(const f32x4*)src;
        f32x4 b = *(const f32x4*)(src + 4);
        s16x8 hi8, lo8;
#pragma unroll
        for (int j = 0; j < 8; j++) {
            float x = (j < 4) ? a[j] : b[j - 4];
            uint32_t u = __float_as_uint(x);
            hi8[j] = (short)(u >> 16);
            lo8[j] = (short)bf16_rn(x - __uint_as_float(u & 0xFFFF0000u));
        }
        int off = ((strip * 16 + s) * 512 + (qg * 16 + lrow) * 8);
        *(s16x8*)&qbuf[off] = hi8;
        *(s16x8*)&qbuf[16384 + off] = lo8;
    }
    lds_barrier();      // qbuf visible; K prime stays in flight

    // ones fragment (bf16 1.0 x8) for the PV row-sum column
    s16x8 onesf;
#pragma unroll
    for (int j = 0; j < 8; j++) onesf[j] = (short)0x3F80;

    f32x4 O[2][8];
#pragma unroll
    for (int st = 0; st < 2; st++)
#pragma unroll
        for (int ct = 0; ct < 8; ct++) O[st][ct] = 0.f;
    f32x4 Osum[2];                  // running softmax denominators (same recurrence as O)
    Osum[0] = 0.f; Osum[1] = 0.f;
    f32x4 m_run[2];
    m_run[0] = -3e38f; m_run[1] = -3e38f;

    for (int tile = 0; tile < ntl; tile++) {
        // ================= S phase: depth-2 pipeline, prefetch wraps into next tile ==========
        f32x4 C[2][2];
        C[0][0] = 0.f; C[0][1] = 0.f; C[1][0] = 0.f; C[1][1] = 0.f;
        __builtin_amdgcn_s_setprio(1);          // MFMA-dense region: prefer this wave
#pragma unroll
        for (int s = 0; s < 16; s++) S_STEP(tile, s);
        __builtin_amdgcn_s_setprio(0);
        // mask tail keys
        if (tile == ntl - 1) {
#pragma unroll
            for (int cb = 0; cb < 2; cb++) {
                int kg = koff + tile * 128 + ch * 32 + cb * 16 + l15;
                if (kg >= NK) { C[0][cb] = -3e38f; C[1][cb] = -3e38f; }
            }
        }

        // PV B prologue: key-slice groups sk=0,1 (8 ct-frags each) -- in flight through softmax
        const unsigned short* mtp = MT + (size_t)(ch * 128 + l15) * NK + koff + tile * 128 + q4 * 8;
        s16x8 btg[2][8];
#pragma unroll
        for (int ct = 0; ct < 8; ct++) {
            btg[0][ct] = *(const s16x8*)(mtp + (size_t)ct * 16 * NK);
            btg[1][ct] = *(const s16x8*)(mtp + (size_t)ct * 16 * NK + 32);
        }

        // ================= softmax (max only -- sums come from PV) =================
        f32x4 mx[2];
#pragma unroll
        for (int st = 0; st < 2; st++)
#pragma unroll
            for (int v = 0; v < 4; v++) mx[st][v] = fmaxf(C[st][0][v], C[st][1][v]);
#pragma unroll
        for (int d = 1; d < 16; d <<= 1) {
#pragma unroll
            for (int st = 0; st < 2; st++)
#pragma unroll
                for (int v = 0; v < 4; v++) mx[st][v] = fmaxf(mx[st][v], __shfl_xor(mx[st][v], d, 16));
        }
        if (l15 == 0) {
            *(f32x4*)&smaxb[(ch * 2 + 0) * 16 + q4 * 4] = mx[0];
            *(f32x4*)&smaxb[(ch * 2 + 1) * 16 + q4 * 4] = mx[1];
        }
        lds_barrier();   // B1 (lgkm only -- K/btg prefetches stay in flight)
        f32x4 mnew[2]; mnew[0] = m_run[0]; mnew[1] = m_run[1];
#pragma unroll
        for (int cc = 0; cc < 4; cc++) {
#pragma unroll
            for (int st = 0; st < 2; st++) {
                f32x4 tv = *(const f32x4*)&smaxb[(cc * 2 + st) * 16 + q4 * 4];
#pragma unroll
                for (int v = 0; v < 4; v++) mnew[st][v] = fmaxf(mnew[st][v], tv[v]);
            }
        }
        f32x4 alpha[2];
#pragma unroll
        for (int st = 0; st < 2; st++)
#pragma unroll
            for (int v = 0; v < 4; v++) {
                alpha[st][v] = __expf(m_run[st][v] - mnew[st][v]);
                m_run[st][v] = mnew[st][v];
            }
#pragma unroll
        for (int st = 0; st < 2; st++) {
#pragma unroll
            for (int cb = 0; cb < 2; cb++) {
#pragma unroll
                for (int v = 0; v < 4; v++) {
                    float p = __expf(C[st][cb][v] - mnew[st][v]);
                    pbuf[(ch * 2 + st) * 512 + ((cb * 2 + kq) * 16 + q4 * 4 + v) * 8 + jj] = bf16_rn(p);
                }
            }
        }
        lds_barrier();   // B2: pbuf visible to all waves before pa reads
#pragma unroll
        for (int st = 0; st < 2; st++) {
#pragma unroll
            for (int ct = 0; ct < 8; ct++)
#pragma unroll
                for (int v = 0; v < 4; v++) O[st][ct][v] *= alpha[st][v];
#pragma unroll
            for (int v = 0; v < 4; v++) Osum[st][v] *= alpha[st][v];
        }

        // ================= PV phase: sk-outer, group prefetch distance >= 1 group ============
        __builtin_amdgcn_s_setprio(1);          // MFMA-dense region: prefer this wave
#pragma unroll
        for (int sk = 0; sk < 4; sk++) {
            s16x8 pa0 = *(const s16x8*)&pbuf[((sk * 2 + 0) * 512) + l * 8];
            s16x8 pa1 = *(const s16x8*)&pbuf[((sk * 2 + 1) * 512) + l * 8];
            s16x8 b0 = btg[sk & 1][0], b1 = btg[sk & 1][1], b2 = btg[sk & 1][2], b3 = btg[sk & 1][3];
            s16x8 b4 = btg[sk & 1][4], b5 = btg[sk & 1][5], b6 = btg[sk & 1][6], b7 = btg[sk & 1][7];
            if (sk < 2) {
#pragma unroll
                for (int ct = 0; ct < 8; ct++)
                    btg[sk & 1][ct] = *(const s16x8*)(mtp + (size_t)ct * 16 * NK + (sk + 2) * 32);
            }
            O[0][0] = __builtin_amdgcn_mfma_f32_16x16x32_bf16(pa0, b0, O[0][0], 0, 0, 0);
            O[1][0] = __builtin_amdgcn_mfma_f32_16x16x32_bf16(pa1, b0, O[1][0], 0, 0, 0);
            O[0][1] = __builtin_amdgcn_mfma_f32_16x16x32_bf16(pa0, b1, O[0][1], 0, 0, 0);
            O[1][1] = __builtin_amdgcn_mfma_f32_16x16x32_bf16(pa1, b1, O[1][1], 0, 0, 0);
            O[0][2] = __builtin_amdgcn_mfma_f32_16x16x32_bf16(pa0, b2, O[0][2], 0, 0, 0);
            O[1][2] = __builtin_amdgcn_mfma_f32_16x16x32_bf16(pa1, b2, O[1][2], 0, 0, 0);
            O[0][3] = __builtin_amdgcn_mfma_f32_16x16x32_bf16(pa0, b3, O[0][3], 0, 0, 0);
            O[1][3] = __builtin_amdgcn_mfma_f32_16x16x32_bf16(pa1, b3, O[1][3], 0, 0, 0);
            O[0][4] = __builtin_amdgcn_mfma_f32_16x16x32_bf16(pa0, b4, O[0][4], 0, 0, 0);
            O[1][4] = __builtin_amdgcn_mfma_f32_16x16x32_bf16(pa1, b4, O[1][4], 0, 0, 0);
            O[0][5] = __builtin_amdgcn_mfma_f32_16x16x32_bf16(pa0, b5, O[0][5], 0, 0, 0);
            O[1][5] = __builtin_amdgcn_mfma_f32_16x16x32_bf16(pa1, b5, O[1][5], 0, 0, 0);
            O[0][6] = __builtin_amdgcn_mfma_f32_16x16x32_bf16(pa0, b6, O[0][6], 0, 0, 0);
            O[1][6] = __builtin_amdgcn_mfma_f32_16x16x32_bf16(pa1, b6, O[1][6], 0, 0, 0);
            O[0][7] = __builtin_amdgcn_mfma_f32_16x16x32_bf16(pa0, b7, O[0][7], 0, 0, 0);
            O[1][7] = __builtin_amdgcn_mfma_f32_16x16x32_bf16(pa1, b7, O[1][7], 0, 0, 0);
            // row-sum column: Osum += P . ones  (exact fp32 accumulate of the same bf16(p))
            Osum[0] = __builtin_amdgcn_mfma_f32_16x16x32_bf16(pa0, onesf, Osum[0], 0, 0, 0);
            Osum[1] = __builtin_amdgcn_mfma_f32_16x16x32_bf16(pa1, onesf, Osum[1], 0, 0, 0);
        }
        __builtin_amdgcn_s_setprio(0);
        // no trailing barrier: B1 of the next iteration orders pa-reads vs pbuf-writes
    }

    // ================= epilogue =================
    if (nsplit == 2) {
        float* Od = Opart + (size_t)split * NQ * RD;
#pragma unroll
        for (int st = 0; st < 2; st++)
#pragma unroll
            for (int ct = 0; ct < 8; ct++)
#pragma unroll
                for (int v = 0; v < 4; v++)
                    Od[(size_t)(qbase + st * 16 + q4 * 4 + v) * RD + ch * 128 + ct * 16 + l15] =
                        O[st][ct][v];
        if (ch == 0 && l15 == 0) {
#pragma unroll
            for (int st = 0; st < 2; st++)
#pragma unroll
                for (int v = 0; v < 4; v++) {
                    mpart[split * NQ + qbase + st * 16 + q4 * 4 + v] = m_run[st][v];
                    lpart[split * NQ + qbase + st * 16 + q4 * 4 + v] = Osum[st][v];
                }
        }
    } else {
#pragma unroll
        for (int st = 0; st < 2; st++)
#pragma unroll
            for (int ct = 0; ct < 8; ct++)
#pragma unroll
                for (int v = 0; v < 4; v++)
                    out[(size_t)(qbase + st * 16 + q4 * 4 + v) * RD + ch * 128 + ct * 16 + l15] =
                        O[st][ct][v] / Osum[st][v];
    }
}

// ---------------- combine split-K partials ----------------
__global__ __launch_bounds__(256) void combine_kernel(const float* __restrict__ Opart,
                                                      const float* __restrict__ mpart,
                                                      const float* __restrict__ lpart,
                                                      float* __restrict__ out) {
    const int t = threadIdx.x;
    const int row = blockIdx.x * 2 + (t >> 7);
    const int d = (t & 127) * 4;
    float m0 = mpart[row], m1 = mpart[NQ + row];
    float l0 = lpart[row], l1 = lpart[NQ + row];
    float m = fmaxf(m0, m1);
    float w0 = __expf(m0 - m), w1 = __expf(m1 - m);
    float inv = 1.f / (w0 * l0 + w1 * l1);
    f32x4 o0 = *(const f32x4*)&Opart[(size_t)row * RD + d];
    f32x4 o1 = *(const f32x4*)&Opart[(size_t)NQ * RD + (size_t)row * RD + d];
    f32x4 r;
#pragma unroll
    for (int v = 0; v < 4; v++) r[v] = (o0[v] * w0 + o1[v] * w1) * inv;
    *(f32x4*)&out[(size_t)row * RD + d] = r;
}

// ---------------- fallback (ws too small): fp32, slow but exact ----------------
__global__ __launch_bounds__(256) void naive_kernel(const float* __restrict__ h,
                                                    const float* __restrict__ M,
                                                    float* __restrict__ out) {
    __shared__ float hs[16 * 520];
    __shared__ float ms[8 * 520];
    __shared__ float sdot[2][128];
    __shared__ float sm[16], sl[16], sal[16], sp[16][8];
    const int t = threadIdx.x;
    const int qbase = blockIdx.x * 16;
#pragma unroll
    for (int i = 0; i < 32; i++) {
        int e = t + i * 256;
        int row = e >> 9, col = e & 511;
        hs[row * 520 + col] = h[(size_t)(qbase + row) * RD + col];
    }
    if (t < 16) { sm[t] = -3e38f; sl[t] = 0.f; }
    float Oacc[32];
#pragma unroll
    for (int i = 0; i < 32; i++) Oacc[i] = 0.f;
    const int q = t >> 4;
    const int eb = (t & 15) * 32;

    for (int k0 = 0; k0 < NK; k0 += 8) {
        __syncthreads();
#pragma unroll
        for (int i = 0; i < 16; i++) {
            int e = t + i * 256;
            if (e < 4096) {
                int kk = e >> 9, col = e & 511;
                ms[kk * 520 + col] = M[(size_t)(k0 + kk) * RD + col];
            }
        }
        __syncthreads();
        {
            int pair = t & 127, half = t >> 7;
            int qq = pair & 15, kk = pair >> 4;
            const float* hp = &hs[qq * 520 + half * 256];
            const float* mp = &ms[kk * 520 + half * 256];
            float acc = 0.f;
#pragma unroll 8
            for (int e = 0; e < 256; e++) acc += hp[e] * mp[e];
            sdot[half][pair] = acc;
        }
        __syncthreads();
        if (t < 16) {
            int qq = t;
            float s8[8];
#pragma unroll
            for (int kk = 0; kk < 8; kk++) s8[kk] = sdot[0][qq + 16 * kk] + sdot[1][qq + 16 * kk];
            float mn = sm[qq];
#pragma unroll
            for (int kk = 0; kk < 8; kk++) mn = fmaxf(mn, s8[kk]);
            float al = __expf(sm[qq] - mn);
            float addl = 0.f;
#pragma unroll
            for (int kk = 0; kk < 8; kk++) { float p = __expf(s8[kk] - mn); sp[qq][kk] = p; addl += p; }
            sm[qq] = mn; sl[qq] = sl[qq] * al + addl; sal[qq] = al;
        }
        __syncthreads();
        {
            float al = sal[q];
#pragma unroll
            for (int i = 0; i < 32; i++) Oacc[i] *= al;
#pragma unroll
            for (int kk = 0; kk < 8; kk++) {
                float p = sp[q][kk];
                const float* mp = &ms[kk * 520 + eb];
#pragma unroll
                for (int i = 0; i < 32; i++) Oacc[i] += p * mp[i];
            }
        }
    }
    __syncthreads();
    float inv = 1.f / sl[q];
#pragma unroll
    for (int i = 0; i < 32; i++) out[(size_t)(qbase + q) * RD + eb + i] = Oacc[i] * inv;
}

extern "C" void kernel_launch(void* const* d_in, const int* in_sizes, int n_in,
                              void* d_out, int out_size, void* d_ws, size_t ws_size,
                              hipStream_t stream) {
    const float* h = (const float*)d_in[0];
    const float* M = (const float*)d_in[1];
    float* out = (float*)d_out;
    const size_t seg = (size_t)NK * RD;                      // u16 elems per converted buffer
    // Mhi + Mlo + MT + 8K u16 pad (tail reads stay in d_ws; 0xAA poison = finite bf16)
    const size_t base_bytes = (seg * 3ull + 8192ull) * 2ull;
    const size_t opart_bytes = 2ull * NQ * RD * 4ull;
    const size_t stat_bytes = 2ull * 2ull * NQ * 4ull;
    const size_t need_split = base_bytes + opart_bytes + stat_bytes;

    if (ws_size >= base_bytes) {
        unsigned short* Mhi = (unsigned short*)d_ws;
        unsigned short* Mlo = Mhi + seg;
        unsigned short* MT  = Mlo + seg;
        float* Opart = (float*)((char*)d_ws + base_bytes);
        float* mpart = Opart + 2ull * NQ * RD;
        float* lpart = mpart + 2ull * NQ;
        preconv_kernel<<<dim3(313, 8), 256, 0, stream>>>(M, Mhi, Mlo, MT);
        if (ws_size >= need_split) {
            flash25_kernel<<<512, 256, 0, stream>>>(h, Mhi, Mlo, MT, out, Opart, mpart, lpart, 2);
            combine_kernel<<<NQ / 2, 256, 0, stream>>>(Opart, mpart, lpart, out);
        } else {
            flash25_kernel<<<256, 256, 0, stream>>>(h, Mhi, Mlo, MT, out, Opart, mpart, lpart, 1);
        }
    } else {
        naive_kernel<<<512, 256, 0, stream>>>(h, M, out);
    }
}